// Round 2
// baseline (285.758 us; speedup 1.0000x reference)
//
#include <hip/hip_runtime.h>
#include <hip/hip_cooperative_groups.h>

namespace cg = cooperative_groups;

#define LEVEL 256
#define BLOCKS 8
// B=16, H=W=1024, bm=bn=128, tv = 16384/256*10 = 640

// ---------------------------------------------------------------------------
// Fused cooperative kernel: one workgroup per 128x128 image block.
// Phase 1: load block (coalesced float4), LDS histogram via atomics, park
//          pixels in LDS packed 4x u8 per u32 (16 KB).
//          clip -> scan -> u8 map table -> global maps8.
// grid.sync()
// Phase 2: build 4 quadrant-packed {lu,lb,ru,rb} u32 tables from neighbor
//          maps, map own pixels from LDS, coalesced float4 stores.
// Grid = 1024 blocks x 256 thr = 4 blocks/CU x 256 CU (co-resident: LDS
// 23.6 KB/block, __launch_bounds__(256,4) caps VGPR at 128).
// ---------------------------------------------------------------------------
__global__ __launch_bounds__(256, 4) void clahe_fused(const float* __restrict__ img,
                                                      float* __restrict__ out,
                                                      unsigned char* __restrict__ maps8) {
#pragma clang fp contract(off)
    __shared__ unsigned int pix[4096];   // 16 KB: 16384 px, 4 per u32
    __shared__ int   hist[256];
    __shared__ float red[256];
    __shared__ float scan[256];
    __shared__ unsigned int tab[1024];   // 4 quadrant tables, packed bytes
    __shared__ float s_me;

    const int t   = threadIdx.x;
    const int bid = blockIdx.x;          // 0..1023
    const int b   = bid >> 6;            // image
    const int br  = (bid >> 3) & 7;
    const int bc  = bid & 7;

    hist[t] = 0;
    __syncthreads();

    const size_t base = (size_t)b * 1048576 + (size_t)(br * 128) * 1024 + (size_t)(bc * 128);
    const float* p = img + base;
#pragma unroll 4
    for (int it = 0; it < 16; ++it) {
        int idx = it * 256 + t;          // 0..4095
        int y   = idx >> 5;              // 0..127
        int x   = (idx & 31) * 4;        // 0..124
        float4 v = *(const float4*)(p + (size_t)y * 1024 + x);
        int va = (int)v.x, vb = (int)v.y, vc = (int)v.z, vd = (int)v.w;
        atomicAdd(&hist[va], 1);
        atomicAdd(&hist[vb], 1);
        atomicAdd(&hist[vc], 1);
        atomicAdd(&hist[vd], 1);
        pix[idx] = (unsigned)va | ((unsigned)vb << 8) | ((unsigned)vc << 16) | ((unsigned)vd << 24);
    }
    __syncthreads();

    // clip: tv = 640, redistribute excess uniformly (integer-exact in fp32)
    const float tv = 640.0f;
    float h = (float)hist[t];
    red[t] = fmaxf(h - tv, 0.0f);
    __syncthreads();
    for (int off = 128; off > 0; off >>= 1) {
        if (t < off) red[t] += red[t + off];
        __syncthreads();
    }
    if (t == 0) s_me = red[0] * (1.0f / 256.0f);   // exact: /2^8
    __syncthreads();
    const float me = s_me;
    float clip = floorf(((h >= tv) ? tv : h) + me);

    // inclusive scan over 256 bins (integer-valued -> exact in any order)
    scan[t] = clip;
    __syncthreads();
    for (int off = 1; off < 256; off <<= 1) {
        float add = (t >= off) ? scan[t - off] : 0.0f;
        __syncthreads();
        scan[t] += add;
        __syncthreads();
    }
    float cdf = scan[t] * (255.0f / 16384.0f);     // exact scale: 255/2^14
    int m = ((int)floorf(cdf)) & 255;
    maps8[(size_t)bid * 256 + t] = (unsigned char)m;

    __threadfence();          // device-scope release of map bytes (cross-XCD)
    cg::this_grid().sync();
    __threadfence();          // device-scope acquire before reading neighbors

    // ---- build 4 quadrant tables: q = qi*2+qj, qi/qj select row/col half ----
    const int r0 = (br > 0) ? (br - 1) : 0;   // rows 0..63   -> r = r0
    const int r1 = br;                         // rows 64..127 -> r = r1
    const int c0 = (bc > 0) ? (bc - 1) : 0;
    const int c1 = bc;
    const unsigned char* mb = maps8 + (size_t)b * 16384;
#pragma unroll
    for (int q = 0; q < 4; ++q) {
        int rq  = (q & 2) ? r1 : r0;
        int cq  = (q & 1) ? c1 : c0;
        int rpq = min(rq + 1, BLOCKS - 1);
        int cpq = min(cq + 1, BLOCKS - 1);
        unsigned lu = mb[(rq  * 8 + cq ) * 256 + t];
        unsigned lb = mb[(rpq * 8 + cq ) * 256 + t];
        unsigned ru = mb[(rq  * 8 + cpq) * 256 + t];
        unsigned rb = mb[(rpq * 8 + cpq) * 256 + t];
        tab[q * 256 + t] = lu | (lb << 8) | (ru << 16) | (rb << 24);
    }
    __syncthreads();

    // ---- map phase: column (and thus y1, quadrant-col) fixed per thread ----
    const int colq = (t & 31) * 4;            // 0..124 within block
    const int qj   = colq >> 6;               // 0 or 1
    const int cq   = qj ? c1 : c0;
    const bool cEdge = (cq >= BLOCKS - 1);
    const float cbase = (float)(cq * 128 + 64);
    const int jg = bc * 128 + colq;           // global col
    float y1v[4], y0v[4];
#pragma unroll
    for (int k = 0; k < 4; ++k) {
        y1v[k] = cEdge ? 0.0f : ((float)(jg + k) - cbase) * 0.0078125f;
        y0v[k] = 1.0f - y1v[k];
    }

#pragma unroll
    for (int it = 0; it < 16; ++it) {
        const int qi  = (it >= 8) ? 1 : 0;          // 8 rows/iter, never crosses 64
        const int rq  = qi ? r1 : r0;
        const bool rEdge = (rq >= BLOCKS - 1);
        const int row = it * 8 + (t >> 5);          // 0..127
        const int ig  = br * 128 + row;             // global row
        const float x1 = rEdge ? 0.0f : ((float)ig - (float)(rq * 128 + 64)) * 0.0078125f;
        const float x0 = 1.0f - x1;

        const unsigned w = pix[it * 256 + t];
        const unsigned* tb = &tab[(qi * 2 + qj) * 256];

        float4 o4;
        float* ov = (float*)&o4;
#pragma unroll
        for (int k = 0; k < 4; ++k) {
            const int v = (w >> (8 * k)) & 255;
            const unsigned mm = tb[v];
            // exact integers 0..255 -> v_cvt_f32_ubyte{0..3}
            const float lu = (float)(mm & 255u);
            const float lb = (float)((mm >> 8) & 255u);
            const float ru = (float)((mm >> 16) & 255u);
            const float rb = (float)(mm >> 24);
            // exact expression order of the reference; no FMA contraction
            float o = y0v[k] * (x0 * lu + x1 * lb) + y1v[k] * (x0 * ru + x1 * rb);
            // trunc toward zero then floor-mod 256 (two's-complement & 255)
            ov[k] = (float)(((int)o) & 255);
        }
        *(float4*)(out + base + (size_t)row * 1024 + colq) = o4;
    }
}

// ---------------------------------------------------------------------------
// Fallback path (proven round-0 structure) if cooperative launch fails.
// ---------------------------------------------------------------------------
__global__ __launch_bounds__(256) void clahe_hist_kernel(const float* __restrict__ img,
                                                         unsigned char* __restrict__ maps8,
                                                         unsigned char* __restrict__ u8img) {
    __shared__ int   hist[256];
    __shared__ float red[256];
    __shared__ float scan[256];
    __shared__ float s_me;

    const int t   = threadIdx.x;
    const int bid = blockIdx.x;
    const int b   = bid >> 6;
    const int blk = bid & 63;
    const int br  = blk >> 3;
    const int bc  = blk & 7;

    hist[t] = 0;
    __syncthreads();

    const size_t base = (size_t)b * 1048576 + (size_t)(br * 128) * 1024 + (size_t)(bc * 128);
    const float* p = img + base;
    unsigned char* q8 = u8img ? (u8img + base) : nullptr;
    for (int it = 0; it < 16; ++it) {
        int idx = it * 256 + t;
        int y   = idx >> 5;
        int x   = (idx & 31) * 4;
        float4 v = *(const float4*)(p + (size_t)y * 1024 + x);
        int va = (int)v.x, vb = (int)v.y, vc = (int)v.z, vd = (int)v.w;
        atomicAdd(&hist[va], 1);
        atomicAdd(&hist[vb], 1);
        atomicAdd(&hist[vc], 1);
        atomicAdd(&hist[vd], 1);
        if (q8) {
            uchar4 pk;
            pk.x = (unsigned char)va; pk.y = (unsigned char)vb;
            pk.z = (unsigned char)vc; pk.w = (unsigned char)vd;
            *(uchar4*)(q8 + (size_t)y * 1024 + x) = pk;
        }
    }
    __syncthreads();

    const float tv = 640.0f;
    float h = (float)hist[t];
    red[t] = fmaxf(h - tv, 0.0f);
    __syncthreads();
    for (int off = 128; off > 0; off >>= 1) {
        if (t < off) red[t] += red[t + off];
        __syncthreads();
    }
    if (t == 0) s_me = red[0] * (1.0f / 256.0f);
    __syncthreads();
    const float me = s_me;
    float clip = floorf(((h >= tv) ? tv : h) + me);

    scan[t] = clip;
    __syncthreads();
    for (int off = 1; off < 256; off <<= 1) {
        float add = (t >= off) ? scan[t - off] : 0.0f;
        __syncthreads();
        scan[t] += add;
        __syncthreads();
    }
    float cdf = scan[t] * (255.0f / 16384.0f);
    int m = ((int)floorf(cdf)) & 255;
    maps8[(size_t)bid * 256 + t] = (unsigned char)m;
}

template <bool U8>
__global__ __launch_bounds__(256) void clahe_map_kernel(const float* __restrict__ imgf,
                                                        const unsigned char* __restrict__ img8,
                                                        const unsigned char* __restrict__ maps8,
                                                        float* __restrict__ out) {
#pragma clang fp contract(off)
    __shared__ float4 m4[256];   // {lu, lb, ru, rb} per bin

    const int t  = threadIdx.x;
    const int b  = blockIdx.z;
    const int i0 = blockIdx.y * 64;
    const int j0 = blockIdx.x * 64;

    const int r  = (i0 >= 64) ? ((i0 - 64) >> 7) : 0;
    const int c  = (j0 >= 64) ? ((j0 - 64) >> 7) : 0;
    const int rp = min(r + 1, BLOCKS - 1);
    const int cp = min(c + 1, BLOCKS - 1);
    const bool rEdge = (r >= BLOCKS - 1);
    const bool cEdge = (c >= BLOCKS - 1);

    const unsigned char* mb = maps8 + (size_t)b * 64 * 256;
    {
        float lu = (float)mb[(r  * 8 + c ) * 256 + t];
        float lb = (float)mb[(rp * 8 + c ) * 256 + t];
        float ru = (float)mb[(r  * 8 + cp) * 256 + t];
        float rb = (float)mb[(rp * 8 + cp) * 256 + t];
        m4[t] = make_float4(lu, lb, ru, rb);
    }
    __syncthreads();

    const size_t ibase = (size_t)b * 1048576;
    const int row_in = t >> 4;
    const int col4   = (t & 15) * 4;

    for (int it = 0; it < 4; ++it) {
        const int i = i0 + it * 16 + row_in;
        const int j = j0 + col4;

        int vv[4];
        if (U8) {
            uchar4 px = *(const uchar4*)(img8 + ibase + (size_t)i * 1024 + j);
            vv[0] = px.x; vv[1] = px.y; vv[2] = px.z; vv[3] = px.w;
        } else {
            float4 px = *(const float4*)(imgf + ibase + (size_t)i * 1024 + j);
            vv[0] = (int)px.x; vv[1] = (int)px.y; vv[2] = (int)px.z; vv[3] = (int)px.w;
        }

        const float x1  = rEdge ? 0.0f : ((float)i - (float)(r * 128 + 64)) * 0.0078125f;
        const float x0  = 1.0f - x1;

        float4 o4;
        float* ov = (float*)&o4;
        for (int k = 0; k < 4; ++k) {
            const int jj = j + k;
            const float y1 = cEdge ? 0.0f : ((float)jj - (float)(c * 128 + 64)) * 0.0078125f;
            const float4 q = m4[vv[k]];
            float o = (1.0f - y1) * (x0 * q.x + x1 * q.y)
                    + y1 * (x0 * q.z + x1 * q.w);
            ov[k] = (float)(((int)o) & 255);
        }
        *(float4*)(out + ibase + (size_t)i * 1024 + j) = o4;
    }
}

extern "C" void kernel_launch(void* const* d_in, const int* in_sizes, int n_in,
                              void* d_out, int out_size, void* d_ws, size_t ws_size,
                              hipStream_t stream) {
    const float* img = (const float*)d_in[0];
    float* out = (float*)d_out;
    unsigned char* maps8 = (unsigned char*)d_ws;            // 256 KB

    void* args[] = {(void*)&img, (void*)&out, (void*)&maps8};
    hipError_t e = hipLaunchCooperativeKernel((const void*)clahe_fused,
                                              dim3(1024), dim3(256),
                                              args, 0, stream);
    if (e != hipSuccess) {
        // Fallback: proven two-kernel path.
        const size_t maps_bytes = (size_t)1024 * 256;
        const size_t u8_bytes   = (size_t)16 * 1024 * 1024;
        const bool use_u8 = ws_size >= maps_bytes + u8_bytes;
        unsigned char* u8img = use_u8 ? ((unsigned char*)d_ws + maps_bytes) : nullptr;

        clahe_hist_kernel<<<dim3(1024), dim3(256), 0, stream>>>(img, maps8, u8img);
        if (use_u8) {
            clahe_map_kernel<true><<<dim3(16, 16, 16), dim3(256), 0, stream>>>(
                nullptr, u8img, maps8, out);
        } else {
            clahe_map_kernel<false><<<dim3(16, 16, 16), dim3(256), 0, stream>>>(
                img, nullptr, maps8, out);
        }
    }
}

// Round 5
// 118.497 us; speedup vs baseline: 2.4115x; 2.4115x over previous
//
#include <hip/hip_runtime.h>

#define LEVEL 256
#define BLOCKS 8
// B=16, H=W=1024, bm=bn=128, tv = 16384/256*10 = 640

// ---------------------------------------------------------------------------
// Kernel 1: per-image-block histogram -> clip -> cdf -> u8 map table.
// Also stages the pixel values as uint8 into ws so kernel 2 reads 16 MB
// instead of 64 MB. (Identical to the proven 124-us round-0 kernel except
// maps are stored as exact u8 instead of float.)
// grid = 16*8*8 = 1024 blocks, 256 threads each.
// maps8 layout in ws: uint8 maps8[16][8][8][256]  (256 KB total)
// ---------------------------------------------------------------------------
__global__ __launch_bounds__(256) void clahe_hist_kernel(const float* __restrict__ img,
                                                         unsigned char* __restrict__ maps8,
                                                         unsigned char* __restrict__ u8img) {
    __shared__ int   hist[256];
    __shared__ float red[256];
    __shared__ float scan[256];
    __shared__ float s_me;

    const int t   = threadIdx.x;
    const int bid = blockIdx.x;            // 0..1023
    const int b   = bid >> 6;              // image
    const int blk = bid & 63;
    const int br  = blk >> 3;
    const int bc  = blk & 7;

    hist[t] = 0;
    __syncthreads();

    // 128x128 block = 4096 float4 loads, 16 per thread, coalesced.
    // u8 staging: 32 lanes x 4 B = 128 B per row-chunk -> full-line writes.
    const size_t base = (size_t)b * 1048576 + (size_t)(br * 128) * 1024 + (size_t)(bc * 128);
    const float* p = img + base;
    unsigned char* q8 = u8img ? (u8img + base) : nullptr;
    for (int it = 0; it < 16; ++it) {
        int idx = it * 256 + t;            // 0..4095
        int y   = idx >> 5;                // 0..127
        int x   = (idx & 31) * 4;          // 0..124
        float4 v = *(const float4*)(p + (size_t)y * 1024 + x);
        int va = (int)v.x, vb = (int)v.y, vc = (int)v.z, vd = (int)v.w;
        atomicAdd(&hist[va], 1);
        atomicAdd(&hist[vb], 1);
        atomicAdd(&hist[vc], 1);
        atomicAdd(&hist[vd], 1);
        if (q8) {
            uchar4 pk;
            pk.x = (unsigned char)va; pk.y = (unsigned char)vb;
            pk.z = (unsigned char)vc; pk.w = (unsigned char)vd;
            *(uchar4*)(q8 + (size_t)y * 1024 + x) = pk;
        }
    }
    __syncthreads();

    // clip: tv = 640, redistribute excess uniformly (all integer-exact in fp32)
    const float tv = 640.0f;
    float h = (float)hist[t];
    red[t] = fmaxf(h - tv, 0.0f);
    __syncthreads();
    for (int off = 128; off > 0; off >>= 1) {
        if (t < off) red[t] += red[t + off];
        __syncthreads();
    }
    if (t == 0) s_me = red[0] * (1.0f / 256.0f);   // exact: /2^8
    __syncthreads();
    const float me = s_me;
    float clip = floorf(((h >= tv) ? tv : h) + me);

    // inclusive scan over 256 bins (integer-valued -> exact in any order)
    scan[t] = clip;
    __syncthreads();
    for (int off = 1; off < 256; off <<= 1) {
        float add = (t >= off) ? scan[t - off] : 0.0f;
        __syncthreads();
        scan[t] += add;
        __syncthreads();
    }
    float cdf = scan[t] * (255.0f / 16384.0f);     // exact scale: 255/2^14
    int m = ((int)floorf(cdf)) & 255;
    maps8[(size_t)bid * 256 + t] = (unsigned char)m;   // exact 0..255
}

// ---------------------------------------------------------------------------
// Kernel 2: per-pixel bilinear blend of 4 neighboring block maps.
// 64x128 pixel tile per workgroup:
//   - r constant over the 64 rows (boundaries at i = 64 + 128*m);
//   - columns span two quadrants (left 64 / right 64), handled by TWO
//     packed LDS tables; each thread's column (hence quadrant and y1
//     factors) is FIXED across all row iterations.
//   - u8 load: uchar4, 32 lanes/row -> one full 128-B line per row-chunk.
//   - store: one float4/lane/iter, lanes 0-31 contiguous -> 4 full lines.
//   - table: {lu,lb,ru,rb} packed as 4 bytes in one u32 per bin -> random
//     lookup is ds_read_b32 spread over all 32 banks (~2 lanes/bank, free)
//     instead of float4 ds_read_b128 crowding 8 bank groups.
// grid = (8, 16, 16) = (W/128, H/64, B), 256 threads, 8 iters x 8 rows.
// ---------------------------------------------------------------------------
template <bool U8>
__global__ __launch_bounds__(256) void clahe_map_kernel(const float* __restrict__ imgf,
                                                        const unsigned char* __restrict__ img8,
                                                        const unsigned char* __restrict__ maps8,
                                                        float* __restrict__ out) {
#pragma clang fp contract(off)
    __shared__ unsigned int mL[256];   // packed {lu,lb,ru,rb} for left  64 cols
    __shared__ unsigned int mR[256];   // packed {lu,lb,ru,rb} for right 64 cols

    const int t  = threadIdx.x;
    const int b  = blockIdx.z;
    const int i0 = blockIdx.y * 64;
    const int j0 = blockIdx.x * 128;

    // r = trunc((i-64)/128) toward zero, constant over the 64-row tile
    const int r  = (i0 >= 64) ? ((i0 - 64) >> 7) : 0;
    const int rp = min(r + 1, BLOCKS - 1);
    const bool rEdge = (r >= BLOCKS - 1);

    // column quadrants: left half [j0, j0+64), right half [j0+64, j0+128)
    const int cL  = (j0 >= 64) ? ((j0 - 64) >> 7) : 0;
    const int cR  = j0 >> 7;
    const int cLp = min(cL + 1, BLOCKS - 1);
    const int cRp = min(cR + 1, BLOCKS - 1);

    const unsigned char* mb = maps8 + (size_t)b * 64 * 256;
    {
        unsigned lu = mb[(r  * 8 + cL ) * 256 + t];
        unsigned lb = mb[(rp * 8 + cL ) * 256 + t];
        unsigned ru = mb[(r  * 8 + cLp) * 256 + t];
        unsigned rb = mb[(rp * 8 + cLp) * 256 + t];
        mL[t] = lu | (lb << 8) | (ru << 16) | (rb << 24);
        unsigned lu2 = mb[(r  * 8 + cR ) * 256 + t];
        unsigned lb2 = mb[(rp * 8 + cR ) * 256 + t];
        unsigned ru2 = mb[(r  * 8 + cRp) * 256 + t];
        unsigned rb2 = mb[(rp * 8 + cRp) * 256 + t];
        mR[t] = lu2 | (lb2 << 8) | (ru2 << 16) | (rb2 << 24);
    }
    __syncthreads();

    // per-thread fixed column: j = (t&31)*4 in [0,124]
    const int jc   = (t & 31) * 4;
    const int half = jc >> 6;                 // 0 = left quadrant, 1 = right
    const unsigned int* mt = half ? mR : mL;
    const int cq   = half ? cR : cL;
    const bool cEdge = (cq >= BLOCKS - 1);
    const float cbase = (float)(cq * 128 + 64);

    float y1v[4], y0v[4];
#pragma unroll
    for (int k = 0; k < 4; ++k) {
        y1v[k] = cEdge ? 0.0f : ((float)(j0 + jc + k) - cbase) * 0.0078125f;
        y0v[k] = 1.0f - y1v[k];
    }

    const size_t ibase = (size_t)b * 1048576;
    const float rbase = (float)(r * 128 + 64);
    const int row0 = t >> 5;                  // 0..7

#pragma unroll
    for (int it = 0; it < 8; ++it) {
        const int i = i0 + it * 8 + row0;
        const size_t off = ibase + (size_t)i * 1024 + j0 + jc;

        int vv[4];
        if (U8) {
            uchar4 px = *(const uchar4*)(img8 + off);
            vv[0] = px.x; vv[1] = px.y; vv[2] = px.z; vv[3] = px.w;
        } else {
            float4 px = *(const float4*)(imgf + off);
            vv[0] = (int)px.x; vv[1] = (int)px.y; vv[2] = (int)px.z; vv[3] = (int)px.w;
        }

        const float x1 = rEdge ? 0.0f : ((float)i - rbase) * 0.0078125f;
        const float x0 = 1.0f - x1;

        float4 o4;
        float* ov = (float*)&o4;
#pragma unroll
        for (int k = 0; k < 4; ++k) {
            const unsigned mm = mt[vv[k]];
            // exact integers 0..255 -> v_cvt_f32_ubyte{0..3}
            const float lu = (float)(mm & 255u);
            const float lb = (float)((mm >> 8) & 255u);
            const float ru = (float)((mm >> 16) & 255u);
            const float rb = (float)(mm >> 24);
            // exact expression order of the reference; no FMA contraction
            float o = y0v[k] * (x0 * lu + x1 * lb) + y1v[k] * (x0 * ru + x1 * rb);
            // trunc toward zero then floor-mod 256 (two's-complement & 255)
            ov[k] = (float)(((int)o) & 255);
        }
        *(float4*)(out + off) = o4;
    }
}

extern "C" void kernel_launch(void* const* d_in, const int* in_sizes, int n_in,
                              void* d_out, int out_size, void* d_ws, size_t ws_size,
                              hipStream_t stream) {
    const float* img = (const float*)d_in[0];
    float* out = (float*)d_out;

    unsigned char* maps8 = (unsigned char*)d_ws;            // 256 KB
    const size_t maps_bytes = (size_t)1024 * 256;           // 16*64*256 u8
    const size_t u8_bytes   = (size_t)16 * 1024 * 1024;
    const bool use_u8 = ws_size >= maps_bytes + u8_bytes;
    unsigned char* u8img = use_u8 ? ((unsigned char*)d_ws + maps_bytes) : nullptr;

    clahe_hist_kernel<<<dim3(1024), dim3(256), 0, stream>>>(img, maps8, u8img);
    if (use_u8) {
        clahe_map_kernel<true><<<dim3(8, 16, 16), dim3(256), 0, stream>>>(
            nullptr, u8img, maps8, out);
    } else {
        clahe_map_kernel<false><<<dim3(8, 16, 16), dim3(256), 0, stream>>>(
            img, nullptr, maps8, out);
    }
}